// Round 8
// baseline (679.712 us; speedup 1.0000x reference)
//
#include <hip/hip_runtime.h>
#include <hip/hip_bf16.h>

// Swin-V2 window attention, fused one-block-per-window. All I/O fp32.
// B=32, H=W=64, C=60, NH=6, hd=10, WS=7 -> pad 70, nw=10, 3200 windows x 49 tok.
//
// R17 = R9 byte-exact (213us anchor) + ONE change: the P2/P5 weight-row
//  arrays are no longer kept resident across the token loop. Theory: with
//  VGPR_Count=48 and no scratch traffic, R9's w4[15] (60 floats) lived in
//  AGPRs, costing one v_accvgpr_read per FMA (~120cy/token/wave -- equal to
//  the FMA work itself; explains measured 312K VALU-cy/SIMD vs ~190K
//  static). Fix: opaque pointer (asm "+v") per token iteration forces 15
//  fresh global_load_dwordx4 per token from L1/L2-resident weights --
//  VMEM-pipe issue (no VALU slots), latency hidden by 4.5 waves/SIMD.
//  R15/R16 lessons kept OUT: no online softmax, no fmaf splits, no max tree,
//  no pad skips (isolate one variable). P4 is R9's exact two-pass form.

#define WSZ 7
#define NT 49
#define CH 60
#define IMG 64
#define LOG100F 4.605170185988092f

__global__ __launch_bounds__(384, 5)
void swin_win_attn(const float* __restrict__ x,
                   const float* __restrict__ qkv_w,
                   const float* __restrict__ qkv_b,
                   const float* __restrict__ logit_scale,
                   const float* __restrict__ proj_w,
                   const float* __restrict__ proj_b,
                   float* __restrict__ out)
{
    __shared__ __align__(16) float s_x[NT * CH];      // 2940 f; aliased as s_out after P2
    __shared__ __align__(16) float s_q[6 * NT * 10];  // 2940 f, stride-10 rows
    __shared__ __align__(16) float s_k[6 * NT * 12];  // 3528 f, 48B rows (b128 x3)
    __shared__ __align__(16) float s_v[6 * NT * 12];  // 3528 f  => 51,744 B total

    const int tid  = threadIdx.x;
    const int lane = tid & 63;
    const int wv   = __builtin_amdgcn_readfirstlane(tid >> 6);
    const int w  = blockIdx.x;
    const int b  = w / 100;
    const int wy = (w / 10) % 10;
    const int wx = w % 10;
    const int row0 = wy * WSZ;
    const int col0 = wx * WSZ;

    // ---- Phase 1: stage x tile (49x60, rows 240B) + zero k/v pad words ----
    for (int idx = tid; idx < NT * 15; idx += 384) {
        int t = idx / 15, m = idx - t * 15;
        int r  = row0 + t / WSZ;
        int cc = col0 + t % WSZ;
        float4 v = make_float4(0.f, 0.f, 0.f, 0.f);
        if (r < IMG && cc < IMG)
            v = reinterpret_cast<const float4*>(x + ((b * IMG + r) * IMG + cc) * CH)[m];
        *reinterpret_cast<float4*>(s_x + t * CH + 4 * m) = v;
    }
    for (int idx = tid; idx < 2 * 6 * NT; idx += 384) {  // 588 pad pairs
        int r = idx >> 1, p = idx & 1;
        s_k[r * 12 + 10 + p] = 0.f;
        s_v[r * 12 + 10 + p] = 0.f;
    }
    __syncthreads();

    // ---- Phase 2: qkv. thread = (channel, token-half); 360 slots of 384.
    //      Weight row re-loaded per token via opaque pointer (L1-hot VMEM,
    //      not AGPR-resident); x via same-address LDS b128 broadcast. ----
    if (tid < 360) {
        const int c    = tid % 180;
        const int half = tid / 180;
        const int part = c / 60;
        const int cl   = c - 60 * part;
        const int h = cl / 10, d = cl - 10 * (cl / 10);
        const float4* wp = reinterpret_cast<const float4*>(qkv_w + c * CH);
        const float bias = qkv_b[c];
        const int t0 = half ? 25 : 0, t1 = half ? NT : 25;
        for (int t = t0; t < t1; ++t) {
            const float4* wpt = wp;
            asm volatile("" : "+v"(wpt));    // opaque: fresh loads each iter
            float a = bias;
            const float4* xr = reinterpret_cast<const float4*>(s_x + t * CH);
            #pragma unroll
            for (int m = 0; m < 15; ++m) {
                float4 xv = xr[m];               // broadcast (<=2 addrs per wave)
                float4 wv4 = wpt[m];             // L1/L2-hot dwordx4
                a += xv.x * wv4.x + xv.y * wv4.y + xv.z * wv4.z + xv.w * wv4.w;
            }
            if (part == 0)      s_q[(h * NT + t) * 10 + d] = a;
            else if (part == 1) s_k[(h * NT + t) * 12 + d] = a;
            else                s_v[(h * NT + t) * 12 + d] = a;
        }
    }
    __syncthreads();

    // ---- Phase 3: L2-normalize k rows only (q normalized inside P4) ----
    if (tid < 6 * NT) {
        float* p = s_k + tid * 12;
        float ss = 0.f;
        #pragma unroll
        for (int d = 0; d < 10; ++d) ss += p[d] * p[d];
        float inv = 1.f / fmaxf(sqrtf(ss), 1e-12f);
        #pragma unroll
        for (int d = 0; d < 10; ++d) p[d] *= inv;
    }
    __syncthreads();

    // ---- Phase 4: attention; thread = (head,row); 294 slots, one pass ----
    if (tid < 6 * NT) {
        const int h = tid / NT, i = tid - h * NT;
        float scale = __expf(fminf(logit_scale[h], LOG100F));
        float q[10];
        {
            const float2* qp = reinterpret_cast<const float2*>(s_q + tid * 10);
            #pragma unroll
            for (int d = 0; d < 5; ++d) { float2 t2 = qp[d]; q[2*d] = t2.x; q[2*d+1] = t2.y; }
            float ss = 0.f;
            #pragma unroll
            for (int d = 0; d < 10; ++d) ss += q[d] * q[d];
            float inv = scale / fmaxf(sqrtf(ss), 1e-12f);  // fold scale into q
            #pragma unroll
            for (int d = 0; d < 10; ++d) q[d] *= inv;
        }
        float a[NT];
        const float4* kb = reinterpret_cast<const float4*>(s_k + h * NT * 12);
        #pragma unroll
        for (int j = 0; j < NT; ++j) {
            float4 k0 = kb[j * 3 + 0];
            float4 k1 = kb[j * 3 + 1];
            float4 k2 = kb[j * 3 + 2];   // .z,.w zeroed pads
            a[j] = q[0]*k0.x + q[1]*k0.y + q[2]*k0.z + q[3]*k0.w
                 + q[4]*k1.x + q[5]*k1.y + q[6]*k1.z + q[7]*k1.w
                 + q[8]*k2.x + q[9]*k2.y;
        }
        float m = a[0];
        #pragma unroll
        for (int j = 1; j < NT; ++j) m = fmaxf(m, a[j]);
        float s = 0.f;
        #pragma unroll
        for (int j = 0; j < NT; ++j) { float e = __expf(a[j] - m); a[j] = e; s += e; }
        float o[10];
        #pragma unroll
        for (int d = 0; d < 10; ++d) o[d] = 0.f;
        const float4* vb = reinterpret_cast<const float4*>(s_v + h * NT * 12);
        #pragma unroll
        for (int j = 0; j < NT; ++j) {
            float4 v0 = vb[j * 3 + 0];
            float4 v1 = vb[j * 3 + 1];
            float4 v2 = vb[j * 3 + 2];
            float aj = a[j];
            o[0] += aj * v0.x; o[1] += aj * v0.y; o[2] += aj * v0.z; o[3] += aj * v0.w;
            o[4] += aj * v1.x; o[5] += aj * v1.y; o[6] += aj * v1.z; o[7] += aj * v1.w;
            o[8] += aj * v2.x; o[9] += aj * v2.y;
        }
        float inv = 1.f / s;
        float* op = s_x + i * CH + h * 10;   // s_out aliases s_x
        #pragma unroll
        for (int d = 0; d < 5; ++d)
            *reinterpret_cast<float2*>(op + 2 * d) =
                make_float2(o[2*d] * inv, o[2*d+1] * inv);
    }
    __syncthreads();

    // ---- Phase 5: proj. lane<60 = out channel, W-row re-loaded per token
    //      via opaque pointer; tokens over 6 waves ----
    if (lane < 60) {
        const float4* wp = reinterpret_cast<const float4*>(proj_w + lane * CH);
        const float bias = proj_b[lane];
        for (int t = wv; t < NT; t += 6) {
            int r  = row0 + t / WSZ;
            int cc = col0 + t % WSZ;
            const float4* wpt = wp;
            asm volatile("" : "+v"(wpt));    // opaque: fresh loads each iter
            float a = bias;
            const float4* xr = reinterpret_cast<const float4*>(s_x + t * CH);
            #pragma unroll
            for (int m = 0; m < 15; ++m) {
                float4 xv = xr[m];                    // broadcast
                float4 wv4 = wpt[m];                  // L1/L2-hot dwordx4
                a += xv.x * wv4.x + xv.y * wv4.y
                   + xv.z * wv4.z + xv.w * wv4.w;
            }
            if (r < IMG && cc < IMG)
                out[((b * IMG + r) * IMG + cc) * CH + lane] = a;   // coalesced
        }
    }
}

extern "C" void kernel_launch(void* const* d_in, const int* in_sizes, int n_in,
                              void* d_out, int out_size, void* d_ws, size_t ws_size,
                              hipStream_t stream) {
    hipLaunchKernelGGL(swin_win_attn, dim3(3200), dim3(384), 0, stream,
                       (const float*)d_in[0], (const float*)d_in[1],
                       (const float*)d_in[2], (const float*)d_in[3],
                       (const float*)d_in[4], (const float*)d_in[5],
                       (float*)d_out);
}

// Round 9
// 644.525 us; speedup vs baseline: 1.0546x; 1.0546x over previous
//
#include <hip/hip_runtime.h>
#include <hip/hip_bf16.h>

// Swin-V2 window attention, fused one-block-per-window. All I/O fp32.
// B=32, H=W=64, C=60, NH=6, hd=10, WS=7 -> pad 70, nw=10, 3200 windows x 49 tok.
//
// R18 = R9 + token-blocking to amortize the AGPR-move tax.
//  Evidence chain: R9 keeps w4[15] (60f) in AGPRs (VGPR_Count=48, no scratch)
//  -> one v_accvgpr_read per FMA operand = 60 moves/token, equal issue cost
//  to the FMA work (explains 312K measured vs 190K static VALU-cy/SIMD).
//  R17 proved reloading weights from L1 instead is 3x WORSE (latency-bound,
//  VALUBusy 20%). Fix: process T tokens per weight sweep -> moves/token
//  divided by T.  P2: T=5 (5 named accs, halves remapped to 25 tokens each,
//  half1 = tokens 24..48; token 24 double-written with identical value --
//  benign). P5: T=2 pairs + wave-0 tail token 48.
//  NO arrays for blocked state (named scalars only), nothing live across
//  barriers, no runtime indexing -- the R8/R10/R16 spill triggers absent.
//  P1/P3/P4 byte-exact R9.

#define WSZ 7
#define NT 49
#define CH 60
#define IMG 64
#define LOG100F 4.605170185988092f

__global__ __launch_bounds__(384, 5)
void swin_win_attn(const float* __restrict__ x,
                   const float* __restrict__ qkv_w,
                   const float* __restrict__ qkv_b,
                   const float* __restrict__ logit_scale,
                   const float* __restrict__ proj_w,
                   const float* __restrict__ proj_b,
                   float* __restrict__ out)
{
    __shared__ __align__(16) float s_x[NT * CH];      // 2940 f; aliased as s_out after P2
    __shared__ __align__(16) float s_q[6 * NT * 10];  // 2940 f, stride-10 rows
    __shared__ __align__(16) float s_k[6 * NT * 12];  // 3528 f, 48B rows (b128 x3)
    __shared__ __align__(16) float s_v[6 * NT * 12];  // 3528 f  => 51,744 B total

    const int tid  = threadIdx.x;
    const int lane = tid & 63;
    const int wv   = __builtin_amdgcn_readfirstlane(tid >> 6);
    const int w  = blockIdx.x;
    const int b  = w / 100;
    const int wy = (w / 10) % 10;
    const int wx = w % 10;
    const int row0 = wy * WSZ;
    const int col0 = wx * WSZ;

    // ---- Phase 1: stage x tile (49x60, rows 240B) + zero k/v pad words ----
    for (int idx = tid; idx < NT * 15; idx += 384) {
        int t = idx / 15, m = idx - t * 15;
        int r  = row0 + t / WSZ;
        int cc = col0 + t % WSZ;
        float4 v = make_float4(0.f, 0.f, 0.f, 0.f);
        if (r < IMG && cc < IMG)
            v = reinterpret_cast<const float4*>(x + ((b * IMG + r) * IMG + cc) * CH)[m];
        *reinterpret_cast<float4*>(s_x + t * CH + 4 * m) = v;
    }
    for (int idx = tid; idx < 2 * 6 * NT; idx += 384) {  // 588 pad pairs
        int r = idx >> 1, p = idx & 1;
        s_k[r * 12 + 10 + p] = 0.f;
        s_v[r * 12 + 10 + p] = 0.f;
    }
    __syncthreads();

    // ---- Phase 2: qkv. thread = (channel, token-half); 360 slots of 384.
    //      T=5 token blocking: each w4[m] moved from AGPR once per 5 tokens.
    //      half0 = tokens 0..24, half1 = 24..48 (token 24 double-written,
    //      identical value -> benign). ----
    if (tid < 360) {
        const int c    = tid % 180;
        const int half = tid / 180;
        const int part = c / 60;
        const int cl   = c - 60 * part;
        const int h = cl / 10, d = cl - 10 * (cl / 10);
        float4 w4[15];
        const float4* wp = reinterpret_cast<const float4*>(qkv_w + c * CH);
        #pragma unroll
        for (int m = 0; m < 15; ++m) w4[m] = wp[m];
        const float bias = qkv_b[c];
        const int t0 = half ? 24 : 0;            // 25 tokens either way
        for (int g = 0; g < 5; ++g) {
            const int base = t0 + 5 * g;
            const float4* xr0 = reinterpret_cast<const float4*>(s_x + (base + 0) * CH);
            const float4* xr1 = reinterpret_cast<const float4*>(s_x + (base + 1) * CH);
            const float4* xr2 = reinterpret_cast<const float4*>(s_x + (base + 2) * CH);
            const float4* xr3 = reinterpret_cast<const float4*>(s_x + (base + 3) * CH);
            const float4* xr4 = reinterpret_cast<const float4*>(s_x + (base + 4) * CH);
            float a0 = bias, a1 = bias, a2 = bias, a3 = bias, a4 = bias;
            #pragma unroll
            for (int m = 0; m < 15; ++m) {
                float4 wv4 = w4[m];              // 4 AGPR moves per 5 tokens
                float4 x0 = xr0[m];              // broadcast LDS b128
                float4 x1 = xr1[m];
                float4 x2 = xr2[m];
                float4 x3 = xr3[m];
                float4 x4 = xr4[m];
                a0 += x0.x*wv4.x + x0.y*wv4.y + x0.z*wv4.z + x0.w*wv4.w;
                a1 += x1.x*wv4.x + x1.y*wv4.y + x1.z*wv4.z + x1.w*wv4.w;
                a2 += x2.x*wv4.x + x2.y*wv4.y + x2.z*wv4.z + x2.w*wv4.w;
                a3 += x3.x*wv4.x + x3.y*wv4.y + x3.z*wv4.z + x3.w*wv4.w;
                a4 += x4.x*wv4.x + x4.y*wv4.y + x4.z*wv4.z + x4.w*wv4.w;
            }
            if (part == 0) {
                s_q[(h * NT + base + 0) * 10 + d] = a0;
                s_q[(h * NT + base + 1) * 10 + d] = a1;
                s_q[(h * NT + base + 2) * 10 + d] = a2;
                s_q[(h * NT + base + 3) * 10 + d] = a3;
                s_q[(h * NT + base + 4) * 10 + d] = a4;
            } else if (part == 1) {
                s_k[(h * NT + base + 0) * 12 + d] = a0;
                s_k[(h * NT + base + 1) * 12 + d] = a1;
                s_k[(h * NT + base + 2) * 12 + d] = a2;
                s_k[(h * NT + base + 3) * 12 + d] = a3;
                s_k[(h * NT + base + 4) * 12 + d] = a4;
            } else {
                s_v[(h * NT + base + 0) * 12 + d] = a0;
                s_v[(h * NT + base + 1) * 12 + d] = a1;
                s_v[(h * NT + base + 2) * 12 + d] = a2;
                s_v[(h * NT + base + 3) * 12 + d] = a3;
                s_v[(h * NT + base + 4) * 12 + d] = a4;
            }
        }
    }
    __syncthreads();

    // ---- Phase 3: L2-normalize k rows only (q normalized inside P4) ----
    if (tid < 6 * NT) {
        float* p = s_k + tid * 12;
        float ss = 0.f;
        #pragma unroll
        for (int d = 0; d < 10; ++d) ss += p[d] * p[d];
        float inv = 1.f / fmaxf(sqrtf(ss), 1e-12f);
        #pragma unroll
        for (int d = 0; d < 10; ++d) p[d] *= inv;
    }
    __syncthreads();

    // ---- Phase 4: attention; thread = (head,row); 294 slots, one pass ----
    if (tid < 6 * NT) {
        const int h = tid / NT, i = tid - h * NT;
        float scale = __expf(fminf(logit_scale[h], LOG100F));
        float q[10];
        {
            const float2* qp = reinterpret_cast<const float2*>(s_q + tid * 10);
            #pragma unroll
            for (int d = 0; d < 5; ++d) { float2 t2 = qp[d]; q[2*d] = t2.x; q[2*d+1] = t2.y; }
            float ss = 0.f;
            #pragma unroll
            for (int d = 0; d < 10; ++d) ss += q[d] * q[d];
            float inv = scale / fmaxf(sqrtf(ss), 1e-12f);  // fold scale into q
            #pragma unroll
            for (int d = 0; d < 10; ++d) q[d] *= inv;
        }
        float a[NT];
        const float4* kb = reinterpret_cast<const float4*>(s_k + h * NT * 12);
        #pragma unroll
        for (int j = 0; j < NT; ++j) {
            float4 k0 = kb[j * 3 + 0];
            float4 k1 = kb[j * 3 + 1];
            float4 k2 = kb[j * 3 + 2];   // .z,.w zeroed pads
            a[j] = q[0]*k0.x + q[1]*k0.y + q[2]*k0.z + q[3]*k0.w
                 + q[4]*k1.x + q[5]*k1.y + q[6]*k1.z + q[7]*k1.w
                 + q[8]*k2.x + q[9]*k2.y;
        }
        float m = a[0];
        #pragma unroll
        for (int j = 1; j < NT; ++j) m = fmaxf(m, a[j]);
        float s = 0.f;
        #pragma unroll
        for (int j = 0; j < NT; ++j) { float e = __expf(a[j] - m); a[j] = e; s += e; }
        float o[10];
        #pragma unroll
        for (int d = 0; d < 10; ++d) o[d] = 0.f;
        const float4* vb = reinterpret_cast<const float4*>(s_v + h * NT * 12);
        #pragma unroll
        for (int j = 0; j < NT; ++j) {
            float4 v0 = vb[j * 3 + 0];
            float4 v1 = vb[j * 3 + 1];
            float4 v2 = vb[j * 3 + 2];
            float aj = a[j];
            o[0] += aj * v0.x; o[1] += aj * v0.y; o[2] += aj * v0.z; o[3] += aj * v0.w;
            o[4] += aj * v1.x; o[5] += aj * v1.y; o[6] += aj * v1.z; o[7] += aj * v1.w;
            o[8] += aj * v2.x; o[9] += aj * v2.y;
        }
        float inv = 1.f / s;
        float* op = s_x + i * CH + h * 10;   // s_out aliases s_x
        #pragma unroll
        for (int d = 0; d < 5; ++d)
            *reinterpret_cast<float2*>(op + 2 * d) =
                make_float2(o[2*d] * inv, o[2*d+1] * inv);
    }
    __syncthreads();

    // ---- Phase 5: proj. lane<60 = out channel; T=2 token pairs per wave
    //      (t = wv+6k, wv+6k+6 for k=0,2,4,6); wave 0 tail token 48. ----
    if (lane < 60) {
        float4 w4[15];
        const float4* wp = reinterpret_cast<const float4*>(proj_w + lane * CH);
        #pragma unroll
        for (int m = 0; m < 15; ++m) w4[m] = wp[m];
        const float bias = proj_b[lane];
        #pragma unroll
        for (int k = 0; k < 8; k += 2) {
            const int ta = wv + 6 * k;
            const int tb = ta + 6;                 // both <= 47
            const float4* xa = reinterpret_cast<const float4*>(s_x + ta * CH);
            const float4* xb = reinterpret_cast<const float4*>(s_x + tb * CH);
            float aa = bias, ab = bias;
            #pragma unroll
            for (int m = 0; m < 15; ++m) {
                float4 wv4 = w4[m];                // 4 AGPR moves per 2 tokens
                float4 va = xa[m];                 // broadcast
                float4 vb4 = xb[m];
                aa += va.x*wv4.x + va.y*wv4.y + va.z*wv4.z + va.w*wv4.w;
                ab += vb4.x*wv4.x + vb4.y*wv4.y + vb4.z*wv4.z + vb4.w*wv4.w;
            }
            {
                int r  = row0 + ta / WSZ, cc = col0 + ta % WSZ;
                if (r < IMG && cc < IMG)
                    out[((b * IMG + r) * IMG + cc) * CH + lane] = aa;
            }
            {
                int r  = row0 + tb / WSZ, cc = col0 + tb % WSZ;
                if (r < IMG && cc < IMG)
                    out[((b * IMG + r) * IMG + cc) * CH + lane] = ab;
            }
        }
        if (wv == 0) {                             // token 48 (wave-uniform)
            const int t = 48;
            const float4* xr = reinterpret_cast<const float4*>(s_x + t * CH);
            float a = bias;
            #pragma unroll
            for (int m = 0; m < 15; ++m) {
                float4 wv4 = w4[m];
                float4 xv = xr[m];
                a += xv.x*wv4.x + xv.y*wv4.y + xv.z*wv4.z + xv.w*wv4.w;
            }
            int r  = row0 + t / WSZ, cc = col0 + t % WSZ;
            if (r < IMG && cc < IMG)
                out[((b * IMG + r) * IMG + cc) * CH + lane] = a;
        }
    }
}

extern "C" void kernel_launch(void* const* d_in, const int* in_sizes, int n_in,
                              void* d_out, int out_size, void* d_ws, size_t ws_size,
                              hipStream_t stream) {
    hipLaunchKernelGGL(swin_win_attn, dim3(3200), dim3(384), 0, stream,
                       (const float*)d_in[0], (const float*)d_in[1],
                       (const float*)d_in[2], (const float*)d_in[3],
                       (const float*)d_in[4], (const float*)d_in[5],
                       (float*)d_out);
}